// Round 5
// baseline (188.938 us; speedup 1.0000x reference)
//
#include <hip/hip_runtime.h>
#include <hip/hip_bf16.h>
#include <math.h>

// ---------------------------------------------------------------------------
// RotSSM: out[b,Do,t] = C2 @ scan(M @ u)[.,b,t] + D ⊙ u[b,.,t]
// 4-kernel MFMA pipeline, LCH=32 (1024 blocks, 4/CU), recompute strategy:
//   K1: GEMM1 (recomputed later too) + local scan -> chunk totals ONLY
//   K2: tiny exact carry recurrence carry_c = a^32*carry_{c-1} + Tot_{c-1}
//   K3: GEMM1 again + scan seeded with carry + GEMM2 + D⊙u (u from LDS tile)
// Frag formulas (HW-verified): A[m=L&15][k=(L>>4)*8+j], B[k][n=L&15],
// D col=L&15, row=(L>>4)*4+reg.
// ---------------------------------------------------------------------------

typedef __attribute__((ext_vector_type(8))) short short8;   // 8 bf16 (4 VGPRs)
typedef __attribute__((ext_vector_type(4))) float f32x4;

#define TLEN 4096
#define LCH 32
#define NCH 128
#define BSZ 8
#define LDK 264          // shorts per [t] row (256 + 8 pad)
#define LDW 132          // dwords per [t] row

// workspace float offsets
constexpr int MB_OFF   = 0;                           // M bf16 row-major [256][256]
constexpr int CB_OFF   = 32768;                       // C2 bf16 row-major
constexpr int A1_OFF   = 65536;                       // a^1  [128] float2
constexpr int AL_OFF   = 65792;                       // a^32 [128] float2
constexpr int TOT_OFF  = 66048;                       // Tot  [128][8][128] float2
constexpr int CAR_OFF  = TOT_OFF + NCH * BSZ * 256;   // Carry same shape
constexpr int PL_OFF   = CAR_OFF + NCH * BSZ * 256;   // P [64][4][4]
constexpr int NORM_OFF = PL_OFF + 1024;               // norm [64]

__device__ __forceinline__ float bfbits2f(unsigned int bits16) {
  union { unsigned int u; float f; } v; v.u = bits16 << 16; return v.f;
}
__device__ __forceinline__ unsigned int f2bfbits(float f) {
  union { float f; unsigned int u; } v; v.f = f;
  return (v.u + 0x7fffu + ((v.u >> 16) & 1u)) >> 16;   // RNE, finite inputs
}
__device__ __forceinline__ unsigned int pack2(float x, float y) {
  return f2bfbits(x) | (f2bfbits(y) << 16);
}

// ---------------------------------------------------------------------------
// K0a: gamma, norm, expm(skew), a^1 / a^32 per pair. 1 block.
// ---------------------------------------------------------------------------
__global__ __launch_bounds__(256) void k0a_precompute(
    const float* __restrict__ thetas_log, const float* __restrict__ P_param,
    const float* __restrict__ B_param, const float* __restrict__ gamma_log,
    float* __restrict__ ws) {
  __shared__ float tracep[64][4];
  __shared__ double gamma_d[64];
  const int tid = threadIdx.x;
  {
    int h = tid >> 2, q = tid & 3;
    const float* bp = B_param + (h * 4 + q) * 256;
    float s = 0.f;
    for (int i = 0; i < 256; ++i) { float v = bp[i]; s += v * v; }
    tracep[h][q] = s;
  }
  __syncthreads();
  if (tid < 64) {
    int h = tid;
    double g = exp(-exp((double)gamma_log[h]));
    gamma_d[h] = g;
    double tr = (double)tracep[h][0] + tracep[h][1] + tracep[h][2] + tracep[h][3];
    ws[NORM_OFF + h] = (float)sqrt((1.0 - g * g) / tr);
    double A[4][4], E[4][4], Tm[4][4];
    for (int i = 0; i < 4; ++i)
      for (int j = 0; j < 4; ++j)
        A[i][j] = (double)P_param[h * 16 + i * 4 + j] - (double)P_param[h * 16 + j * 4 + i];
    double fro = 0.0;
    for (int i = 0; i < 4; ++i) for (int j = 0; j < 4; ++j) fro += A[i][j] * A[i][j];
    fro = sqrt(fro);
    int s = 0;
    while (fro > 0.25 && s < 30) { fro *= 0.5; ++s; }
    double scl = 1.0;
    for (int q2 = 0; q2 < s; ++q2) scl *= 0.5;
    for (int i = 0; i < 4; ++i) for (int j = 0; j < 4; ++j) A[i][j] *= scl;
    for (int i = 0; i < 4; ++i)
      for (int j = 0; j < 4; ++j) { E[i][j] = (i == j) ? 1.0 : 0.0; Tm[i][j] = E[i][j]; }
    for (int k = 1; k <= 16; ++k) {
      double Tn[4][4];
      for (int i = 0; i < 4; ++i)
        for (int j = 0; j < 4; ++j) {
          double acc = 0.0;
          for (int m = 0; m < 4; ++m) acc += Tm[i][m] * A[m][j];
          Tn[i][j] = acc / (double)k;
        }
      for (int i = 0; i < 4; ++i)
        for (int j = 0; j < 4; ++j) { Tm[i][j] = Tn[i][j]; E[i][j] += Tn[i][j]; }
    }
    for (int q2 = 0; q2 < s; ++q2) {
      double E2[4][4];
      for (int i = 0; i < 4; ++i)
        for (int j = 0; j < 4; ++j) {
          double acc = 0.0;
          for (int m = 0; m < 4; ++m) acc += E[i][m] * E[m][j];
          E2[i][j] = acc;
        }
      for (int i = 0; i < 4; ++i) for (int j = 0; j < 4; ++j) E[i][j] = E2[i][j];
    }
    for (int i = 0; i < 4; ++i)
      for (int j = 0; j < 4; ++j) ws[PL_OFF + h * 16 + i * 4 + j] = (float)E[i][j];
  }
  __syncthreads();
  if (tid < 128) {
    int h = tid >> 1, p = tid & 1;
    double th = exp((double)thetas_log[h * 2 + p]);
    double g = gamma_d[h];
    double ar = g * cos(th), ai = g * sin(th);
    ((float2*)(ws + A1_OFF))[tid] = make_float2((float)ar, (float)ai);
    double xr = ar, xi = ai;
    for (int q = 0; q < 5; ++q) {          // a^(2^5) = a^32 = a^LCH
      double nr = xr * xr - xi * xi, ni = 2.0 * xr * xi;
      xr = nr; xi = ni;
    }
    ((float2*)(ws + AL_OFF))[tid] = make_float2((float)xr, (float)xi);
  }
}

// ---------------------------------------------------------------------------
// K0b: M = norm*(P@B), C2 = C@blockdiag(P^T) -> plain row-major bf16.
// ---------------------------------------------------------------------------
__global__ __launch_bounds__(256) void k0b_mats(
    const float* __restrict__ B_param, const float* __restrict__ C,
    float* __restrict__ ws) {
  const float* Pl  = ws + PL_OFF;
  const float* nrm = ws + NORM_OFF;
  unsigned short* Mbf = (unsigned short*)(ws + MB_OFF);
  unsigned short* Cbf = (unsigned short*)(ws + CB_OFF);
  const int blk = blockIdx.x, tid = threadIdx.x;
  if (blk < 16) {
    for (int rr = 0; rr < 16; ++rr) {
      int r = blk * 16 + rr, h = r >> 2, N = r & 3;
      float acc = 0.f;
      for (int n = 0; n < 4; ++n)
        acc += Pl[h * 16 + N * 4 + n] * B_param[(h * 4 + n) * 256 + tid];
      Mbf[r * 256 + tid] = (unsigned short)f2bfbits(nrm[h] * acc);
    }
  } else {
    int h = tid >> 2, N = tid & 3;       // tid = state-column index k = 4h+N
    for (int rr = 0; rr < 16; ++rr) {
      int Do = (blk - 16) * 16 + rr;
      float acc = 0.f;
      for (int n = 0; n < 4; ++n)
        acc += C[Do * 256 + (tid & ~3) + n] * Pl[h * 16 + N * 4 + n];
      Cbf[Do * 256 + tid] = (unsigned short)f2bfbits(acc);
    }
  }
}

// ---------------------------------------------------------------------------
// K1: stage u -> GEMM1 -> local scan (zero-init) -> chunk totals only.
// LDS 16896 B, u tile aliased by W tile.
// ---------------------------------------------------------------------------
__global__ __launch_bounds__(256) void k1_tot(
    const float* __restrict__ u, float* __restrict__ ws) {
  __shared__ __align__(16) unsigned char smem[LCH * LDK * 2];   // 16896 B
  unsigned short* us = (unsigned short*)smem;
  unsigned int*   wd = (unsigned int*)smem;      // alias

  const int c = blockIdx.x, b = blockIdx.y;
  const int t0 = c * LCH;
  const int tid = threadIdx.x;
  const int L = tid & 63;
  const int w = __builtin_amdgcn_readfirstlane(tid >> 6);
  const int qh = L >> 4, l15 = L & 15;

  // stage u[d][t0+t] -> us[t][d ^ ((t&3)<<3)]
  {
    const int kbase = tid >> 3, t4 = (tid & 7) * 4;
#pragma unroll
    for (int i = 0; i < 8; ++i) {
      int d = kbase + i * 32;
      float4 v = *(const float4*)(u + (size_t)(b * 256 + d) * TLEN + t0 + t4);
      float vv[4] = {v.x, v.y, v.z, v.w};
#pragma unroll
      for (int dt = 0; dt < 4; ++dt)
        us[(t4 + dt) * LDK + (d ^ (dt << 3))] = (unsigned short)f2bfbits(vv[dt]);
    }
  }
  __syncthreads();

  // GEMM1: W[256][32] = M @ u_tile
  f32x4 acc[4][2];
#pragma unroll
  for (int rt = 0; rt < 4; ++rt)
#pragma unroll
    for (int tt = 0; tt < 2; ++tt) acc[rt][tt] = (f32x4){0.f, 0.f, 0.f, 0.f};
  {
    const unsigned short* Mbf = (const unsigned short*)(ws + MB_OFF);
#pragma unroll
    for (int ks = 0; ks < 8; ++ks) {
      short8 af[4], bf[2];
#pragma unroll
      for (int rt = 0; rt < 4; ++rt)
        af[rt] = *(const short8*)(Mbf + (size_t)(w * 64 + rt * 16 + l15) * 256 + ks * 32 + qh * 8);
#pragma unroll
      for (int tt = 0; tt < 2; ++tt) {
        int row = tt * 16 + l15;
        int col = (ks * 32 + qh * 8) ^ ((row & 3) << 3);
        bf[tt] = *(const short8*)(us + row * LDK + col);
      }
#pragma unroll
      for (int rt = 0; rt < 4; ++rt)
#pragma unroll
        for (int tt = 0; tt < 2; ++tt)
          acc[rt][tt] = __builtin_amdgcn_mfma_f32_16x16x32_bf16(af[rt], bf[tt], acc[rt][tt], 0, 0, 0);
    }
  }
  __syncthreads();   // us reads done before alias overwrite

  // W -> wd[t][p] pair-packed bf16
#pragma unroll
  for (int rt = 0; rt < 4; ++rt) {
    int pbase = w * 32 + rt * 8 + qh * 2;
#pragma unroll
    for (int tt = 0; tt < 2; ++tt) {
      int t = tt * 16 + l15;
      f32x4 a4 = acc[rt][tt];
      *(uint2*)&wd[t * LDW + pbase] = make_uint2(pack2(a4[0], a4[1]), pack2(a4[2], a4[3]));
    }
  }
  __syncthreads();

  // local scan (zero init), totals only
  if (tid < 128) {
    const int p = tid;
    float2 a = ((const float2*)(ws + A1_OFF))[p];
    float zr = 0.f, zi = 0.f;
#pragma unroll
    for (int t = 0; t < LCH; ++t) {
      unsigned int wv = wd[t * LDW + p];
      float wr = bfbits2f(wv & 0xffffu), wi = bfbits2f(wv >> 16);
      float nr = fmaf(a.x, zr, fmaf(-a.y, zi, wr));
      float ni = fmaf(a.x, zi, fmaf(a.y, zr, wi));
      zr = nr; zi = ni;
    }
    ((float2*)(ws + TOT_OFF))[(c * BSZ + b) * 128 + p] = make_float2(zr, zi);
  }
}

// ---------------------------------------------------------------------------
// K2: exact cross-chunk carry recurrence. 8 blocks x 128 threads.
//   carry_0 = 0; carry_c = a^32 * carry_{c-1} + Tot_{c-1}
// ---------------------------------------------------------------------------
__global__ __launch_bounds__(128) void k2_carry(float* __restrict__ ws) {
  const int b = blockIdx.x, p = threadIdx.x;
  const float2 aL = ((const float2*)(ws + AL_OFF))[p];
  const float2* Tot = (const float2*)(ws + TOT_OFF);
  float2* Car = (float2*)(ws + CAR_OFF);
  float cr = 0.f, ci = 0.f;
  Car[(0 * BSZ + b) * 128 + p] = make_float2(0.f, 0.f);
  for (int c = 1; c < NCH; ++c) {
    float2 tv = Tot[((c - 1) * BSZ + b) * 128 + p];
    float nr = fmaf(aL.x, cr, fmaf(-aL.y, ci, tv.x));
    float ni = fmaf(aL.x, ci, fmaf(aL.y, cr, tv.y));
    cr = nr; ci = ni;
    Car[(c * BSZ + b) * 128 + p] = make_float2(cr, ci);
  }
}

// ---------------------------------------------------------------------------
// K3: stage u (kept) -> GEMM1 -> scan seeded with carry -> GEMM2 -> out.
// LDS: us 16896 + wd 16896 = 33792 B (4 blocks/CU).
// ---------------------------------------------------------------------------
__global__ __launch_bounds__(256) void k3_fused(
    const float* __restrict__ u, const float* __restrict__ Dv,
    const float* __restrict__ ws, float* __restrict__ out) {
  __shared__ __align__(16) unsigned char smem[2 * LCH * LDK * 2];
  unsigned short* us = (unsigned short*)smem;                       // u tile
  unsigned int*   wd = (unsigned int*)(smem + LCH * LDK * 2);       // W/z tile

  const int c = blockIdx.x, b = blockIdx.y;
  const int t0 = c * LCH;
  const int tid = threadIdx.x;
  const int L = tid & 63;
  const int w = __builtin_amdgcn_readfirstlane(tid >> 6);
  const int qh = L >> 4, l15 = L & 15;

  // stage u
  {
    const int kbase = tid >> 3, t4 = (tid & 7) * 4;
#pragma unroll
    for (int i = 0; i < 8; ++i) {
      int d = kbase + i * 32;
      float4 v = *(const float4*)(u + (size_t)(b * 256 + d) * TLEN + t0 + t4);
      float vv[4] = {v.x, v.y, v.z, v.w};
#pragma unroll
      for (int dt = 0; dt < 4; ++dt)
        us[(t4 + dt) * LDK + (d ^ (dt << 3))] = (unsigned short)f2bfbits(vv[dt]);
    }
  }
  __syncthreads();

  // GEMM1
  f32x4 acc[4][2];
#pragma unroll
  for (int rt = 0; rt < 4; ++rt)
#pragma unroll
    for (int tt = 0; tt < 2; ++tt) acc[rt][tt] = (f32x4){0.f, 0.f, 0.f, 0.f};
  {
    const unsigned short* Mbf = (const unsigned short*)(ws + MB_OFF);
#pragma unroll
    for (int ks = 0; ks < 8; ++ks) {
      short8 af[4], bf[2];
#pragma unroll
      for (int rt = 0; rt < 4; ++rt)
        af[rt] = *(const short8*)(Mbf + (size_t)(w * 64 + rt * 16 + l15) * 256 + ks * 32 + qh * 8);
#pragma unroll
      for (int tt = 0; tt < 2; ++tt) {
        int row = tt * 16 + l15;
        int col = (ks * 32 + qh * 8) ^ ((row & 3) << 3);
        bf[tt] = *(const short8*)(us + row * LDK + col);
      }
#pragma unroll
      for (int rt = 0; rt < 4; ++rt)
#pragma unroll
        for (int tt = 0; tt < 2; ++tt)
          acc[rt][tt] = __builtin_amdgcn_mfma_f32_16x16x32_bf16(af[rt], bf[tt], acc[rt][tt], 0, 0, 0);
    }
  }

  // W -> wd (separate region; no hazard with us)
#pragma unroll
  for (int rt = 0; rt < 4; ++rt) {
    int pbase = w * 32 + rt * 8 + qh * 2;
#pragma unroll
    for (int tt = 0; tt < 2; ++tt) {
      int t = tt * 16 + l15;
      f32x4 a4 = acc[rt][tt];
      *(uint2*)&wd[t * LDW + pbase] = make_uint2(pack2(a4[0], a4[1]), pack2(a4[2], a4[3]));
    }
  }
  __syncthreads();

  // scan seeded with carry: z_{-1} = carry  =>  z_t = s_t + a^{t+1}*carry
  if (tid < 128) {
    const int p = tid;
    float2 a = ((const float2*)(ws + A1_OFF))[p];
    float2 cv = ((const float2*)(ws + CAR_OFF))[(c * BSZ + b) * 128 + p];
    float zr = cv.x, zi = cv.y;
#pragma unroll
    for (int t = 0; t < LCH; ++t) {
      unsigned int wv = wd[t * LDW + p];
      float wr = bfbits2f(wv & 0xffffu), wi = bfbits2f(wv >> 16);
      float nr = fmaf(a.x, zr, fmaf(-a.y, zi, wr));
      float ni = fmaf(a.x, zi, fmaf(a.y, zr, wi));
      zr = nr; zi = ni;
      wd[t * LDW + p] = pack2(zr, zi);
    }
  }
  __syncthreads();

  // GEMM2: out_tile = C2 @ Z
#pragma unroll
  for (int rt = 0; rt < 4; ++rt)
#pragma unroll
    for (int tt = 0; tt < 2; ++tt) acc[rt][tt] = (f32x4){0.f, 0.f, 0.f, 0.f};
  {
    const unsigned short* Cbf = (const unsigned short*)(ws + CB_OFF);
    const unsigned short* zs  = (const unsigned short*)wd;
#pragma unroll
    for (int ks = 0; ks < 8; ++ks) {
      short8 af[4], bf[2];
#pragma unroll
      for (int rt = 0; rt < 4; ++rt)
        af[rt] = *(const short8*)(Cbf + (size_t)(w * 64 + rt * 16 + l15) * 256 + ks * 32 + qh * 8);
#pragma unroll
      for (int tt = 0; tt < 2; ++tt)
        bf[tt] = *(const short8*)(zs + (tt * 16 + l15) * LDK + ks * 32 + qh * 8);
#pragma unroll
      for (int rt = 0; rt < 4; ++rt)
#pragma unroll
        for (int tt = 0; tt < 2; ++tt)
          acc[rt][tt] = __builtin_amdgcn_mfma_f32_16x16x32_bf16(af[rt], bf[tt], acc[rt][tt], 0, 0, 0);
    }
  }

  // epilogue: out = acc + D ⊙ u   (u bf16 from us tile)
#pragma unroll
  for (int rt = 0; rt < 4; ++rt) {
    int Dbase = w * 64 + rt * 16 + qh * 4;
    float dv[4];
#pragma unroll
    for (int q = 0; q < 4; ++q) dv[q] = Dv[Dbase + q];
#pragma unroll
    for (int tt = 0; tt < 2; ++tt) {
      int t = tt * 16 + l15;
      f32x4 a4 = acc[rt][tt];
      size_t obase = (size_t)(b * 256 + Dbase) * TLEN + t0 + t;
#pragma unroll
      for (int q = 0; q < 4; ++q) {
        float uu = bfbits2f(us[t * LDK + ((Dbase + q) ^ ((t & 3) << 3))]);
        out[obase + (size_t)q * TLEN] = a4[q] + dv[q] * uu;
      }
    }
  }
}

extern "C" void kernel_launch(void* const* d_in, const int* in_sizes, int n_in,
                              void* d_out, int out_size, void* d_ws, size_t ws_size,
                              hipStream_t stream) {
  const float* u          = (const float*)d_in[0];
  const float* thetas_log = (const float*)d_in[1];
  const float* P_param    = (const float*)d_in[2];
  const float* B_param    = (const float*)d_in[3];
  const float* C          = (const float*)d_in[4];
  const float* Dvec       = (const float*)d_in[5];
  const float* gamma_log  = (const float*)d_in[6];
  float* out = (float*)d_out;
  float* ws  = (float*)d_ws;

  hipLaunchKernelGGL(k0a_precompute, dim3(1), dim3(256), 0, stream,
                     thetas_log, P_param, B_param, gamma_log, ws);
  hipLaunchKernelGGL(k0b_mats, dim3(32), dim3(256), 0, stream, B_param, C, ws);
  hipLaunchKernelGGL(k1_tot, dim3(NCH, BSZ), dim3(256), 0, stream, u, ws);
  hipLaunchKernelGGL(k2_carry, dim3(BSZ), dim3(128), 0, stream, ws);
  hipLaunchKernelGGL(k3_fused, dim3(NCH, BSZ), dim3(256), 0, stream, u, Dvec, ws, out);
}